// Round 3
// baseline (510.414 us; speedup 1.0000x reference)
//
#include <hip/hip_runtime.h>
#include <hip/hip_bf16.h>
#include <stdint.h>

// Problem-fixed shapes
#define B_ 8
#define S_ 2048
#define F_ 2048
#define M_ (B_*S_)   // 16384 rows (b*S+s)
#define K_ F_
#define N_ F_

typedef __attribute__((ext_vector_type(4))) float f32x4;
typedef __attribute__((ext_vector_type(8))) short short8;

// ---------- helpers ----------
__device__ __forceinline__ unsigned short f2bf(float f){
  unsigned u = __float_as_uint(f);
  u += 0x7FFFu + ((u >> 16) & 1u);   // round-to-nearest-even
  return (unsigned short)(u >> 16);
}

__device__ __forceinline__ void gload16(const void* g, const void* l){
  __builtin_amdgcn_global_load_lds(
      (const __attribute__((address_space(1))) void*)g,
      (__attribute__((address_space(3))) void*)l,
      16, 0, 0);
}

__device__ __forceinline__ float waveReduce(float v){
  #pragma unroll
  for (int off = 32; off; off >>= 1) v += __shfl_down(v, off, 64);
  return v;
}

// 256-thread block reduce, result broadcast to all threads
__device__ __forceinline__ float blockReduceAll(float v, float* sbuf){
  v = waveReduce(v);
  int lane = threadIdx.x & 63, w = threadIdx.x >> 6;
  __syncthreads();
  if (lane == 0) sbuf[w] = v;
  __syncthreads();
  return sbuf[0] + sbuf[1] + sbuf[2] + sbuf[3];
}

// ---------- 1) scale = mean(|W|) ----------
// W has F*F = 4,194,304 elems; 4096 blocks x 256 thr x 4 elems covers exactly.
__global__ __launch_bounds__(256) void k_abs1(const float* __restrict__ W, float* __restrict__ part){
  __shared__ float sb[4];
  size_t idx = ((size_t)blockIdx.x * 256 + threadIdx.x) * 4;
  f32x4 v = *(const f32x4*)(W + idx);
  float s = fabsf(v[0]) + fabsf(v[1]) + fabsf(v[2]) + fabsf(v[3]);
  s = blockReduceAll(s, sb);
  if (threadIdx.x == 0) part[blockIdx.x] = s;
}

__global__ __launch_bounds__(256) void k_abs2(const float* __restrict__ part, float* __restrict__ scalep){
  __shared__ float sb[4];
  float s = 0.f;
  int t = threadIdx.x;
  #pragma unroll
  for (int i = 0; i < 16; i++) s += part[t + i*256];   // 4096 partials
  s = blockReduceAll(s, sb);
  if (t == 0) scalep[0] = s * (1.0f / ((float)F_ * (float)F_));
}

// ---------- 2) quantize W -> ternary bf16, transposed: BT[g][f] ----------
__global__ __launch_bounds__(256) void k_quantT(const float* __restrict__ W, unsigned short* __restrict__ BT,
                                                const float* __restrict__ scalep){
  __shared__ float tile[32][33];
  int gx = blockIdx.x * 32;  // g offset (cols of W)
  int fy = blockIdx.y * 32;  // f offset (rows of W)
  int tx = threadIdx.x & 31, ty = threadIdx.x >> 5;   // 32 x 8
  float inv = 1.0f / (scalep[0] + 1e-8f);
  #pragma unroll
  for (int i = 0; i < 4; i++){
    int f = fy + ty + i*8;
    tile[ty + i*8][tx] = W[(size_t)f * F_ + gx + tx];
  }
  __syncthreads();
  #pragma unroll
  for (int i = 0; i < 4; i++){
    int g = gx + ty + i*8;
    float w = tile[tx][ty + i*8];           // = W[fy+tx][g]
    float t = rintf(w * inv);
    t = fminf(1.0f, fmaxf(-1.0f, t));
    BT[(size_t)g * K_ + fy + tx] = f2bf(t); // exact for {-1,0,1}
  }
}

// ---------- 3) x -> bf16 (XH) fused with la_raw = x @ w_left + b_left ----------
__global__ __launch_bounds__(256) void k_conv_la(const float* __restrict__ X, const float* __restrict__ wl,
                                                 const float* __restrict__ bl, unsigned short* __restrict__ XH,
                                                 float* __restrict__ la_raw){
  __shared__ float sb[4];
  int row = blockIdx.x;
  const float* xr = X + (size_t)row * F_;
  unsigned short* xh = XH + (size_t)row * F_;
  int t = threadIdx.x;
  float s = 0.f;
  #pragma unroll
  for (int i = 0; i < 2; i++){
    int base = t*4 + i*1024;
    f32x4 v  = *(const f32x4*)(xr + base);
    f32x4 wv = *(const f32x4*)(wl + base);
    s += v[0]*wv[0] + v[1]*wv[1] + v[2]*wv[2] + v[3]*wv[3];
    ushort4 p;
    p.x = f2bf(v[0]); p.y = f2bf(v[1]); p.z = f2bf(v[2]); p.w = f2bf(v[3]);
    *(ushort4*)(xh + base) = p;
  }
  s = blockReduceAll(s, sb);
  if (t == 0) la_raw[row] = s + bl[0];
}

// ---------- 4) ra_raw[b][f] = sum_s x[b,s,f] * w_right[s] (partial, atomic) ----------
__global__ __launch_bounds__(256) void k_ra(const float* __restrict__ X, const float* __restrict__ wrt,
                                            float* __restrict__ ra_raw){
  int f  = blockIdx.x * 256 + threadIdx.x;
  int b  = blockIdx.y;
  int s0 = blockIdx.z * 256;
  const float* xb = X + (size_t)b * S_ * F_ + (size_t)s0 * F_ + f;
  float acc = 0.f;
  #pragma unroll 8
  for (int s = 0; s < 256; ++s)
    acc += xb[(size_t)s * F_] * wrt[s0 + s];
  atomicAdd(&ra_raw[b * F_ + f], acc);
}

// ---------- 5) LN over S, relu, x/(x+eps) ----------
__global__ __launch_bounds__(256) void k_ln_la(const float* __restrict__ la_raw, float* __restrict__ la){
  __shared__ float sb[4];
  int b = blockIdx.x;
  const float* p = la_raw + b * S_;
  int t = threadIdx.x;
  float v[8]; float s = 0.f, s2 = 0.f;
  #pragma unroll
  for (int i = 0; i < 8; i++){ v[i] = p[t + i*256]; s += v[i]; s2 += v[i]*v[i]; }
  s  = blockReduceAll(s,  sb);
  s2 = blockReduceAll(s2, sb);
  float mu  = s * (1.0f / S_);
  float var = s2 * (1.0f / S_) - mu*mu;
  float rstd = 1.0f / sqrtf(var + 1e-5f);
  #pragma unroll
  for (int i = 0; i < 8; i++){
    float x = (v[i] - mu) * rstd;
    x = fmaxf(x, 0.0f);
    la[b * S_ + t + i*256] = x / (x + 1e-6f);
  }
}

// ---------- 6) LN over F, relu, normalize by sum ----------
__global__ __launch_bounds__(256) void k_ln_ra(const float* __restrict__ ra_raw, const float* __restrict__ br,
                                               float* __restrict__ ra){
  __shared__ float sb[4];
  int b = blockIdx.x;
  const float* p = ra_raw + b * F_;
  int t = threadIdx.x;
  float bb = br[0];
  float v[8]; float s = 0.f, s2 = 0.f;
  #pragma unroll
  for (int i = 0; i < 8; i++){ v[i] = p[t + i*256] + bb; s += v[i]; s2 += v[i]*v[i]; }
  s  = blockReduceAll(s,  sb);
  s2 = blockReduceAll(s2, sb);
  float mu  = s * (1.0f / F_);
  float var = s2 * (1.0f / F_) - mu*mu;
  float rstd = 1.0f / sqrtf(var + 1e-5f);
  float r[8]; float sr = 0.f;
  #pragma unroll
  for (int i = 0; i < 8; i++){ r[i] = fmaxf((v[i] - mu) * rstd, 0.0f); sr += r[i]; }
  sr = blockReduceAll(sr, sb);
  float invs = 1.0f / (sr + 1e-6f);
  #pragma unroll
  for (int i = 0; i < 8; i++) ra[b * F_ + t + i*256] = r[i] * invs;
}

// ---------- 7) GEMM (bf16 MFMA 16x16x32, 128x128 tile) + fused epilogue ----------
// A = XH [M][K] bf16; B^T = BT [N][K] bf16 (BT[g][f] = Tq[f][g]).
// out = (1-a)*x + a * la[row] * (acc*scale + b_v[g]) * ra[b][g]
__global__ __launch_bounds__(256) void k_gemm(
    const unsigned short* __restrict__ A, const unsigned short* __restrict__ BT,
    const float* __restrict__ X, const float* __restrict__ la, const float* __restrict__ ra,
    const float* __restrict__ bv, const float* __restrict__ alphap, const float* __restrict__ scalep,
    float* __restrict__ Out)
{
  __shared__ __align__(128) char lds[16384];   // A-tile 8KB | B-tile 8KB
  const int NBX = N_ / 128;                    // 16
  int tid = threadIdx.x;
  int bid = blockIdx.x;
  const int nwg = (M_/128) * (N_/128);         // 2048, divisible by 8 -> simple XCD swizzle
  int cpx = nwg >> 3;
  int swz = (bid & 7) * cpx + (bid >> 3);
  int brow = swz / NBX, bcol = swz % NBX;
  int row0 = brow * 128, col0 = bcol * 128;

  int w = tid >> 6, lane = tid & 63;
  int wr = w >> 1, wc = w & 1;                 // 2x2 waves, each 64x64
  int lrow = lane & 15, kgrp = lane >> 4;

  f32x4 acc[4][4];
  #pragma unroll
  for (int m = 0; m < 4; m++)
    #pragma unroll
    for (int n = 0; n < 4; n++) acc[m][n] = (f32x4)(0.0f);

  // staging: tile is [128 rows][32 cols] bf16 = 4 chunks of 16B per row.
  // LDS stays LINEAR (chunk c at byte c*16); the XOR swizzle (kb ^ (row&3)) is
  // applied on the GLOBAL source and on the ds_read side (both-sides rule).
  int c0 = tid, c1 = tid + 256;
  int ar0 = c0 >> 2, ak0 = (((c0 & 3) ^ (ar0 & 3)) << 3);
  int ar1 = c1 >> 2, ak1 = (((c1 & 3) ^ (ar1 & 3)) << 3);
  const unsigned short* Ap0 = A  + (size_t)(row0 + ar0) * K_ + ak0;
  const unsigned short* Ap1 = A  + (size_t)(row0 + ar1) * K_ + ak1;
  const unsigned short* Bp0 = BT + (size_t)(col0 + ar0) * K_ + ak0;
  const unsigned short* Bp1 = BT + (size_t)(col0 + ar1) * K_ + ak1;
  char* ldsA = lds;
  char* ldsB = lds + 8192;
  const void* dA0 = ldsA + w*1024;          // + lane*16 implicit (wave-uniform base)
  const void* dA1 = ldsA + 4096 + w*1024;
  const void* dB0 = ldsB + w*1024;
  const void* dB1 = ldsB + 4096 + w*1024;

  int aoff[4], boff[4];
  #pragma unroll
  for (int m = 0; m < 4; m++){
    int r  = wr*64 + m*16 + lrow;
    aoff[m] = r*64 + ((kgrp ^ (r & 3)) << 4);
    int rc = wc*64 + m*16 + lrow;
    boff[m] = rc*64 + ((kgrp ^ (rc & 3)) << 4);
  }

  for (int kt = 0; kt < K_/32; ++kt){
    gload16(Ap0, dA0); gload16(Ap1, dA1);
    gload16(Bp0, dB0); gload16(Bp1, dB1);
    Ap0 += 32; Ap1 += 32; Bp0 += 32; Bp1 += 32;
    asm volatile("s_waitcnt vmcnt(0)" ::: "memory");
    __syncthreads();
    short8 af[4], bf[4];
    #pragma unroll
    for (int m = 0; m < 4; m++) af[m] = *(const short8*)(ldsA + aoff[m]);
    #pragma unroll
    for (int n = 0; n < 4; n++) bf[n] = *(const short8*)(ldsB + boff[n]);
    #pragma unroll
    for (int m = 0; m < 4; m++)
      #pragma unroll
      for (int n = 0; n < 4; n++)
        acc[m][n] = __builtin_amdgcn_mfma_f32_16x16x32_bf16(af[m], bf[n], acc[m][n], 0, 0, 0);
    __syncthreads();
  }

  // epilogue
  float a = alphap[0];
  float scale = scalep[0];
  float oma = 1.0f - a;
  int bidx = row0 >> 11;                       // row0 / S_
  const float* rab = ra + bidx * F_;
  #pragma unroll
  for (int m = 0; m < 4; m++){
    int rbase = row0 + wr*64 + m*16 + (lane >> 4) * 4;
    float lav[4];
    #pragma unroll
    for (int r = 0; r < 4; r++) lav[r] = la[rbase + r];
    #pragma unroll
    for (int n = 0; n < 4; n++){
      int col = col0 + wc*64 + n*16 + (lane & 15);
      float rav = rab[col];
      float bvv = bv[col];
      #pragma unroll
      for (int r = 0; r < 4; r++){
        int row = rbase + r;
        float v = acc[m][n][r] * scale + bvv;
        size_t idx = (size_t)row * N_ + col;
        Out[idx] = oma * X[idx] + a * lav[r] * v * rav;
      }
    }
  }
}

// ---------- launch ----------
extern "C" void kernel_launch(void* const* d_in, const int* in_sizes, int n_in,
                              void* d_out, int out_size, void* d_ws, size_t ws_size,
                              hipStream_t stream){
  const float* x     = (const float*)d_in[0];
  // d_in[1] seq_pos_code, d_in[2] feature_pos_code: unused by reference
  const float* Wv    = (const float*)d_in[3];
  const float* bv    = (const float*)d_in[4];
  const float* wl    = (const float*)d_in[5];
  const float* bl    = (const float*)d_in[6];
  const float* wrt   = (const float*)d_in[7];
  const float* br    = (const float*)d_in[8];
  const float* alpha = (const float*)d_in[9];
  float* out = (float*)d_out;

  char* ws = (char*)d_ws;
  unsigned short* XH = (unsigned short*)(ws);              // 67,108,864 B
  unsigned short* BT = (unsigned short*)(ws + 67108864);   //  8,388,608 B
  float* la_raw = (float*)(ws + 75497472);                 // 65,536 B
  float* la     = (float*)(ws + 75563008);                 // 65,536 B
  float* ra_raw = (float*)(ws + 75628544);                 // 65,536 B
  float* ra     = (float*)(ws + 75694080);                 // 65,536 B
  float* part   = (float*)(ws + 75759616);                 // 16,384 B (4096 partials)
  float* scalep = (float*)(ws + 75776000);                 //    256 B

  hipMemsetAsync(ra_raw, 0, B_ * F_ * sizeof(float), stream);
  k_abs1<<<4096, 256, 0, stream>>>(Wv, part);
  k_abs2<<<1, 256, 0, stream>>>(part, scalep);
  k_quantT<<<dim3(F_/32, F_/32), 256, 0, stream>>>(Wv, BT, scalep);
  k_conv_la<<<M_, 256, 0, stream>>>(x, wl, bl, XH, la_raw);
  k_ra<<<dim3(F_/256, B_, S_/256), 256, 0, stream>>>(x, wrt, ra_raw);
  k_ln_la<<<B_, 256, 0, stream>>>(la_raw, la);
  k_ln_ra<<<B_, 256, 0, stream>>>(ra_raw, br, ra);
  k_gemm<<<2048, 256, 0, stream>>>(XH, BT, x, la, ra, bv, alpha, scalep, out);
}